// Round 3
// baseline (883.632 us; speedup 1.0000x reference)
//
#include <hip/hip_runtime.h>
#include <hip/hip_bf16.h>

#define DIM 256
#define NH 8
#define HD 32
#define INV_SCALE 0.17677669529663687f   // 1/sqrt(32)
#define SM_EPS 1e-16f

// ---------- helpers ----------
__device__ __forceinline__ float bf2f(unsigned short u) {
    return __uint_as_float(((unsigned int)u) << 16);
}
__device__ __forceinline__ unsigned short f2bf(float f) {
    unsigned int u = __float_as_uint(f);
    u += 0x7FFFu + ((u >> 16) & 1u);     // round-to-nearest-even
    return (unsigned short)(u >> 16);
}
__device__ __forceinline__ float ldf(float v) { return v; }
__device__ __forceinline__ float ldf(unsigned short v) { return bf2f(v); }

// ---------- dtype sniffer ----------
// flag=1 => float tensors are bf16; flag=0 => fp32.
// Even ushort positions of fp32 data are low-mantissa junk (uniform exponent
// field, ~17% "sane"); of bf16 data they are real values (~100% sane).
__global__ void sniff_kernel(const unsigned short* __restrict__ x,
                             int* __restrict__ flag) {
    int lane = threadIdx.x & 63;
    unsigned short u = x[lane * 2];
    int e = (u >> 7) & 0xFF;
    bool sane = ((u & 0x7FFFu) == 0) || (e >= 0x66 && e <= 0x90);
    unsigned long long m = __ballot(sane);
    if (lane == 0) *flag = (__popcll(m) >= 32) ? 1 : 0;
}

// ---------- init: zero agg + segsum ----------
__global__ __launch_bounds__(256) void init_kernel(float* __restrict__ agg,
                                                   float* __restrict__ segsum,
                                                   int N) {
    int idx = blockIdx.x * 256 + threadIdx.x;
    if (idx < N * DIM) agg[idx] = 0.0f;
    if (idx < N * NH) segsum[idx] = 0.0f;
}

// ---------- GEMM: C[M,256] = A[M,256] @ B[256,256] + bias (+ residual) ------
// AK: 0 = A is an input tensor (dtype per flag), 1 = A is fp32 workspace.
// OK: 0 = output dtype per flag, 1 = fp32 workspace, 2 = bf16 workspace.
// B/bias/res are always input tensors (dtype per flag).
template <int AK, int OK, bool RES>
__global__ __launch_bounds__(256) void gemm256(
        const void* __restrict__ A, const void* __restrict__ B,
        const void* __restrict__ bias, const void* __restrict__ res,
        void* __restrict__ C, size_t outOff, int M, const int* __restrict__ flag)
{
    const bool m16 = (*flag != 0);
    constexpr int BM = 64, BN = 64, BK = 16;
    __shared__ float As[BK][BM + 1];
    __shared__ float Bs[BK][BN];
    const int tid  = threadIdx.x;
    const int row0 = blockIdx.x * BM;
    const int col0 = blockIdx.y * BN;
    const int lm = tid >> 2;             // 0..63   A-tile row
    const int lk = (tid & 3) << 2;       // 0,4,8,12 A-tile k quad
    const int bk = tid >> 4;             // 0..15   B-tile k
    const int bn = (tid & 15) << 2;      // 0..60   B-tile col quad
    const int tr = (tid >> 4) << 2;      // out row base in tile
    const int tc = (tid & 15) << 2;      // out col base in tile

    float acc[4][4] = {};

    for (int k0 = 0; k0 < DIM; k0 += BK) {
        float a0, a1, a2, a3;
        const int am = row0 + lm;
        if (am < M) {
            const size_t aidx = (size_t)am * DIM + k0 + lk;
            if constexpr (AK == 1) {
                float4 v = *(const float4*)((const float*)A + aidx);
                a0 = v.x; a1 = v.y; a2 = v.z; a3 = v.w;
            } else {
                if (m16) {
                    ushort4 v = *(const ushort4*)((const unsigned short*)A + aidx);
                    a0 = bf2f(v.x); a1 = bf2f(v.y); a2 = bf2f(v.z); a3 = bf2f(v.w);
                } else {
                    float4 v = *(const float4*)((const float*)A + aidx);
                    a0 = v.x; a1 = v.y; a2 = v.z; a3 = v.w;
                }
            }
        } else {
            a0 = a1 = a2 = a3 = 0.0f;
        }
        As[lk + 0][lm] = a0; As[lk + 1][lm] = a1;
        As[lk + 2][lm] = a2; As[lk + 3][lm] = a3;

        const size_t bidx = (size_t)(k0 + bk) * DIM + col0 + bn;
        if (m16) {
            ushort4 bv = *(const ushort4*)((const unsigned short*)B + bidx);
            Bs[bk][bn + 0] = bf2f(bv.x); Bs[bk][bn + 1] = bf2f(bv.y);
            Bs[bk][bn + 2] = bf2f(bv.z); Bs[bk][bn + 3] = bf2f(bv.w);
        } else {
            float4 bv = *(const float4*)((const float*)B + bidx);
            Bs[bk][bn + 0] = bv.x; Bs[bk][bn + 1] = bv.y;
            Bs[bk][bn + 2] = bv.z; Bs[bk][bn + 3] = bv.w;
        }

        __syncthreads();
        #pragma unroll
        for (int kk = 0; kk < BK; ++kk) {
            float ar[4];
            #pragma unroll
            for (int i = 0; i < 4; ++i) ar[i] = As[kk][tr + i];
            float4 b4 = *(const float4*)&Bs[kk][tc];
            float br[4] = {b4.x, b4.y, b4.z, b4.w};
            #pragma unroll
            for (int i = 0; i < 4; ++i)
                #pragma unroll
                for (int j = 0; j < 4; ++j)
                    acc[i][j] += ar[i] * br[j];
        }
        __syncthreads();
    }

    float bval[4];
    #pragma unroll
    for (int j = 0; j < 4; ++j) {
        bval[j] = m16 ? bf2f(((const unsigned short*)bias)[col0 + tc + j])
                      : ((const float*)bias)[col0 + tc + j];
    }

    #pragma unroll
    for (int i = 0; i < 4; ++i) {
        const int r = row0 + tr + i;
        if (r < M) {
            #pragma unroll
            for (int j = 0; j < 4; ++j) {
                float v = acc[i][j] + bval[j];
                const size_t ridx = (size_t)r * DIM + col0 + tc + j;
                if constexpr (RES) {
                    v += m16 ? bf2f(((const unsigned short*)res)[ridx])
                             : ((const float*)res)[ridx];
                }
                const size_t oidx = outOff + ridx;
                if constexpr (OK == 1) {
                    ((float*)C)[oidx] = v;
                } else if constexpr (OK == 2) {
                    ((unsigned short*)C)[oidx] = f2bf(v);
                } else {
                    if (m16) ((unsigned short*)C)[oidx] = f2bf(v);
                    else     ((float*)C)[oidx] = v;
                }
            }
        }
    }
}

// ---------- per-edge: score -> exp (clamped), accumulate segment sum --------
template <typename TQ>
__global__ __launch_bounds__(256) void edge_scores(
        const TQ* __restrict__ Q, const TQ* __restrict__ Kmat,
        const int* __restrict__ src, const int* __restrict__ dst,
        float* __restrict__ sc, float* __restrict__ segsum, int E)
{
    const int e = blockIdx.x;
    const int s = src[e];
    const int d = dst[e];
    const int c = threadIdx.x;
    float p = ldf(Q[(size_t)d * DIM + c]) * ldf(Kmat[(size_t)s * DIM + c]);
    #pragma unroll
    for (int off = 16; off > 0; off >>= 1) p += __shfl_down(p, off, 32);
    if ((c & 31) == 0) {
        const int h = c >> 5;
        float ex = __expf(fminf(p * INV_SCALE, 60.0f));  // clamp: NaN/overflow guard
        sc[(size_t)e * NH + h] = ex;
        atomicAdd(&segsum[(size_t)d * NH + h], ex);
    }
}

// ---------- aggregate: agg[dst] += V[src] * attn ----------
template <typename TV>
__global__ __launch_bounds__(256) void agg_kernel(
        const TV* __restrict__ V, const float* __restrict__ sc,
        const float* __restrict__ segsum, const int* __restrict__ src,
        const int* __restrict__ dst, float* __restrict__ agg, int E)
{
    const int e = blockIdx.x;
    const int s = src[e];
    const int d = dst[e];
    const int c = threadIdx.x;
    const int h = c >> 5;
    float w = sc[(size_t)e * NH + h] / (segsum[(size_t)d * NH + h] + SM_EPS);
    atomicAdd(&agg[(size_t)d * DIM + c], ldf(V[(size_t)s * DIM + c]) * w);
}

// ---------- per-branch driver ----------
template <bool WS_F32>
static void run_branch(const void* x, const int* edges, int N, int E,
                       const void* const* w, void* out, size_t outOff,
                       void* Qv, void* Kv, void* Vv, float* agg, float* sc,
                       float* ssum, const int* flag, hipStream_t stream)
{
    const int* src = edges;
    const int* dst = edges + E;

    hipLaunchKernelGGL(init_kernel, dim3(N), dim3(256), 0, stream, agg, ssum, N);

    dim3 gg((N + 63) / 64, DIM / 64);
    constexpr int OKws = WS_F32 ? 1 : 2;
    hipLaunchKernelGGL((gemm256<0, OKws, false>), gg, dim3(256), 0, stream,
                       x, w[0], w[1], (const void*)nullptr, Qv, (size_t)0, N, flag);
    hipLaunchKernelGGL((gemm256<0, OKws, false>), gg, dim3(256), 0, stream,
                       x, w[2], w[3], (const void*)nullptr, Kv, (size_t)0, N, flag);
    hipLaunchKernelGGL((gemm256<0, OKws, false>), gg, dim3(256), 0, stream,
                       x, w[4], w[5], (const void*)nullptr, Vv, (size_t)0, N, flag);

    if constexpr (WS_F32) {
        hipLaunchKernelGGL((edge_scores<float>), dim3(E), dim3(256), 0, stream,
                           (const float*)Qv, (const float*)Kv, src, dst, sc, ssum, E);
        hipLaunchKernelGGL((agg_kernel<float>), dim3(E), dim3(256), 0, stream,
                           (const float*)Vv, sc, ssum, src, dst, agg, E);
    } else {
        hipLaunchKernelGGL((edge_scores<unsigned short>), dim3(E), dim3(256), 0, stream,
                           (const unsigned short*)Qv, (const unsigned short*)Kv,
                           src, dst, sc, ssum, E);
        hipLaunchKernelGGL((agg_kernel<unsigned short>), dim3(E), dim3(256), 0, stream,
                           (const unsigned short*)Vv, sc, ssum, src, dst, agg, E);
    }

    hipLaunchKernelGGL((gemm256<1, 0, true>), gg, dim3(256), 0, stream,
                       (const void*)agg, w[6], w[7], x, out, outOff, N, flag);
}

// ---------- host ----------
extern "C" void kernel_launch(void* const* d_in, const int* in_sizes, int n_in,
                              void* d_out, int out_size, void* d_ws, size_t ws_size,
                              hipStream_t stream)
{
    const void* slot_x = d_in[0];
    const void* dom_x  = d_in[1];
    const int* slot_edges = (const int*)d_in[2];
    const int* dom_edges  = (const int*)d_in[3];
    const int Ns = in_sizes[0] / DIM;    // 20000
    const int Nd = in_sizes[1] / DIM;    // 1000
    const int Es = in_sizes[2] / 2;      // 320000
    const int Ed = in_sizes[3] / 2;      // 16000

    const void* W[16];
    for (int i = 0; i < 16; ++i) W[i] = d_in[4 + i];

    auto al = [](size_t b) { return (b + 255) & ~(size_t)255; };
    const size_t qkvF = al((size_t)Ns * DIM * 4);   // fp32 Q/K/V each
    const size_t qkvH = al((size_t)Ns * DIM * 2);   // bf16 Q/K/V each
    const size_t aggB = al((size_t)Ns * DIM * 4);
    const size_t scB  = al((size_t)Es * NH * 4);
    const size_t sumB = al((size_t)Ns * NH * 4);
    const size_t needF = 3 * qkvF + aggB + scB + sumB + 1024;

    const bool f32ws = (ws_size >= needF);
    const size_t qkvB = f32ws ? qkvF : qkvH;

    char* p = (char*)d_ws;
    void* Q = p;
    void* K = p + qkvB;
    void* V = p + 2 * qkvB;
    float* agg  = (float*)(p + 3 * qkvB);
    float* sc   = (float*)(p + 3 * qkvB + aggB);
    float* ssum = (float*)(p + 3 * qkvB + aggB + scB);
    int* flag   = (int*)(p + ws_size - 256);   // far end, never overlaps

    hipLaunchKernelGGL(sniff_kernel, dim3(1), dim3(64), 0, stream,
                       (const unsigned short*)slot_x, flag);

    const void* slotW[8] = {W[0], W[1], W[2], W[3], W[4], W[5], W[6], W[7]};
    const void* domW[8]  = {W[8], W[9], W[10], W[11], W[12], W[13], W[14], W[15]};

    // domain branch runs after slot on the same stream -> safe buffer reuse
    if (f32ws) {
        run_branch<true>(slot_x, slot_edges, Ns, Es, slotW, d_out, 0,
                         Q, K, V, agg, sc, ssum, flag, stream);
        run_branch<true>(dom_x, dom_edges, Nd, Ed, domW, d_out,
                         (size_t)Ns * DIM, Q, K, V, agg, sc, ssum, flag, stream);
    } else {
        run_branch<false>(slot_x, slot_edges, Ns, Es, slotW, d_out, 0,
                          Q, K, V, agg, sc, ssum, flag, stream);
        run_branch<false>(dom_x, dom_edges, Nd, Ed, domW, d_out,
                          (size_t)Ns * DIM, Q, K, V, agg, sc, ssum, flag, stream);
    }
}

// Round 4
// 386.260 us; speedup vs baseline: 2.2877x; 2.2877x over previous
//
#include <hip/hip_runtime.h>
#include <hip/hip_bf16.h>

#define DIM 256
#define NH 8
#define INV_SCALE 0.17677669529663687f   // 1/sqrt(32)
#define SM_EPS 1e-16f

typedef unsigned short ushortT;
typedef unsigned int uintT;
typedef __attribute__((ext_vector_type(8))) __bf16 bf16x8;
typedef __attribute__((ext_vector_type(4))) float f32x4;

// ---------- helpers ----------
__device__ __forceinline__ float bf2f(ushortT u) {
    return __uint_as_float(((uintT)u) << 16);
}
__device__ __forceinline__ ushortT f2bf(float f) {
    uintT u = __float_as_uint(f);
    u += 0x7FFFu + ((u >> 16) & 1u);     // round-to-nearest-even
    return (ushortT)(u >> 16);
}

// ---------- dtype sniffer (unchanged from round 3 — it works) ----------
__global__ void sniff_kernel(const ushortT* __restrict__ x, int* __restrict__ flag) {
    int lane = threadIdx.x & 63;
    ushortT u = x[lane * 2];
    int e = (u >> 7) & 0xFF;
    bool sane = ((u & 0x7FFFu) == 0) || (e >= 0x66 && e <= 0x90);
    unsigned long long m = __ballot(sane);
    if (lane == 0) *flag = (__popcll(m) >= 32) ? 1 : 0;
}

// ---------- convert x -> bf16 workspace ----------
__global__ __launch_bounds__(256) void convx_kernel(const void* __restrict__ x,
                                                    ushortT* __restrict__ xb,
                                                    int n4, const int* __restrict__ flag) {
    int i = blockIdx.x * 256 + threadIdx.x;
    if (i >= n4) return;
    if (*flag) {
        ((ushort4*)xb)[i] = ((const ushort4*)x)[i];
    } else {
        float4 v = ((const float4*)x)[i];
        ushort4 o;
        o.x = f2bf(v.x); o.y = f2bf(v.y); o.z = f2bf(v.z); o.w = f2bf(v.w);
        ((ushort4*)xb)[i] = o;
    }
}

// ---------- convert + transpose 4 weights, convert 4 biases ----------
// grid (257, 4): x<256 -> transpose column x of weight y; x==256 -> bias y
__global__ __launch_bounds__(256) void convw_kernel(
        const void* w0, const void* w1, const void* w2, const void* w3,
        const void* b0, const void* b1, const void* b2, const void* b3,
        ushortT* __restrict__ wT, float* __restrict__ biasF,
        const int* __restrict__ flag)
{
    const void* ws_[4] = {w0, w1, w2, w3};
    const void* bs_[4] = {b0, b1, b2, b3};
    int which = blockIdx.y;
    bool m16 = (*flag != 0);
    if (blockIdx.x == 256) {
        const void* b = bs_[which];
        int i = threadIdx.x;
        float v = m16 ? bf2f(((const ushortT*)b)[i]) : ((const float*)b)[i];
        biasF[which * 256 + i] = v;
    } else {
        const void* w = ws_[which];
        int n = blockIdx.x, k = threadIdx.x;
        float v = m16 ? bf2f(((const ushortT*)w)[k * 256 + n])
                      : ((const float*)w)[k * 256 + n];
        wT[(size_t)which * 65536 + n * 256 + k] = f2bf(v);
    }
}

// ---------- CSR build ----------
__global__ __launch_bounds__(256) void csr_zero(int* __restrict__ count, int N) {
    int i = blockIdx.x * 256 + threadIdx.x;
    if (i < N) count[i] = 0;
}
__global__ __launch_bounds__(256) void csr_count(const int* __restrict__ dst,
                                                 int* __restrict__ count, int E) {
    int e = blockIdx.x * 256 + threadIdx.x;
    if (e < E) atomicAdd(&count[dst[e]], 1);
}
// one block, 256 threads: exclusive scan of count[0..N) -> rowptr, cursor
__global__ __launch_bounds__(256) void csr_scan(const int* __restrict__ count,
                                                int* __restrict__ rowptr,
                                                int* __restrict__ cursor, int N) {
    __shared__ int part[256];
    int t = threadIdx.x;
    int chunk = (N + 255) >> 8;
    int base = t * chunk;
    int s = 0;
    for (int j = 0; j < chunk; ++j) {
        int i = base + j;
        if (i < N) s += count[i];
    }
    part[t] = s;
    __syncthreads();
    for (int off = 1; off < 256; off <<= 1) {
        int v = (t >= off) ? part[t - off] : 0;
        __syncthreads();
        part[t] += v;
        __syncthreads();
    }
    int run = (t == 0) ? 0 : part[t - 1];
    for (int j = 0; j < chunk; ++j) {
        int i = base + j;
        if (i < N) {
            rowptr[i] = run;
            cursor[i] = run;
            run += count[i];
        }
    }
    if (base < N && base + chunk >= N) rowptr[N] = run;
}
__global__ __launch_bounds__(256) void csr_scatter(const int* __restrict__ src,
                                                   const int* __restrict__ dst,
                                                   int* __restrict__ cursor,
                                                   int* __restrict__ colsrc, int E) {
    int e = blockIdx.x * 256 + threadIdx.x;
    if (e < E) {
        int pos = atomicAdd(&cursor[dst[e]], 1);
        colsrc[pos] = src[e];
    }
}

// ---------- MFMA GEMM: C[M,256] = A[M,256](bf16) @ BT^T + bias ----------
// BT: bf16 [n][k] (transposed weight). OK: 1 = bf16 ws out, 0 = flag-dtype out.
#define BM 128
#define BN 64
#define BK 32
template <int OK, bool RES>
__global__ __launch_bounds__(256) void gemm_mfma(
        const ushortT* __restrict__ A, const ushortT* __restrict__ BT,
        const float* __restrict__ biasF, const void* __restrict__ res,
        void* __restrict__ C, size_t outOff, int M, const int* __restrict__ flag)
{
    __shared__ ushortT As[BM * BK];
    __shared__ ushortT Bs[BN * BK];
    const int tid  = threadIdx.x;
    const int wid  = tid >> 6;
    const int lane = tid & 63;
    const int row0 = blockIdx.x * BM;
    const int col0 = blockIdx.y * BN;

    const int r_i = tid >> 2;            // 0..63
    const int kq8 = (tid & 3) << 3;      // ushort offset 0,8,16,24
    const int m   = lane & 15;
    const int q   = lane >> 4;

    f32x4 acc[2][4];
    #pragma unroll
    for (int i = 0; i < 2; ++i)
        #pragma unroll
        for (int j = 0; j < 4; ++j)
            acc[i][j] = (f32x4){0.f, 0.f, 0.f, 0.f};

    const size_t rA0 = (size_t)min(row0 + r_i, M - 1) * DIM;
    const size_t rA1 = (size_t)min(row0 + 64 + r_i, M - 1) * DIM;
    const size_t rB  = (size_t)(col0 + r_i) * DIM;

    for (int k0 = 0; k0 < DIM; k0 += BK) {
        uint4 a0v = *(const uint4*)(A + rA0 + k0 + kq8);
        uint4 a1v = *(const uint4*)(A + rA1 + k0 + kq8);
        uint4 bv  = *(const uint4*)(BT + rB + k0 + kq8);
        __syncthreads();
        *(uint4*)&As[r_i * BK + kq8]        = a0v;
        *(uint4*)&As[(64 + r_i) * BK + kq8] = a1v;
        *(uint4*)&Bs[r_i * BK + kq8]        = bv;
        __syncthreads();

        bf16x8 af0 = *(const bf16x8*)&As[(wid * 32 + m) * BK + q * 8];
        bf16x8 af1 = *(const bf16x8*)&As[(wid * 32 + 16 + m) * BK + q * 8];
        #pragma unroll
        for (int j = 0; j < 4; ++j) {
            bf16x8 bf = *(const bf16x8*)&Bs[(j * 16 + m) * BK + q * 8];
            acc[0][j] = __builtin_amdgcn_mfma_f32_16x16x32_bf16(af0, bf, acc[0][j], 0, 0, 0);
            acc[1][j] = __builtin_amdgcn_mfma_f32_16x16x32_bf16(af1, bf, acc[1][j], 0, 0, 0);
        }
    }

    const bool m16 = (*flag != 0);
    #pragma unroll
    for (int i = 0; i < 2; ++i) {
        #pragma unroll
        for (int j = 0; j < 4; ++j) {
            const int col = col0 + j * 16 + m;
            const float bval = biasF[col];
            #pragma unroll
            for (int r = 0; r < 4; ++r) {
                const int row = row0 + wid * 32 + i * 16 + q * 4 + r;
                if (row < M) {
                    float v = acc[i][j][r] + bval;
                    const size_t ridx = (size_t)row * DIM + col;
                    if constexpr (RES) {
                        v += m16 ? bf2f(((const ushortT*)res)[ridx])
                                 : ((const float*)res)[ridx];
                    }
                    if constexpr (OK == 1) {
                        ((ushortT*)C)[ridx] = f2bf(v);
                    } else {
                        if (m16) ((ushortT*)C)[outOff + ridx] = f2bf(v);
                        else     ((float*)C)[outOff + ridx] = v;
                    }
                }
            }
        }
    }
}

// ---------- fused attention: 1 wave per dst node, 4 cols per lane ----------
__global__ __launch_bounds__(64) void attn_kernel(
        const ushortT* __restrict__ Qb, const ushortT* __restrict__ Kb,
        const ushortT* __restrict__ Vb, const int* __restrict__ rowptr,
        const int* __restrict__ colsrc, ushortT* __restrict__ aggb, int N)
{
    const int d = blockIdx.x;
    const int t = threadIdx.x;
    const size_t cbase = (size_t)d * DIM + t * 4;

    uint2 qv = *(const uint2*)(Qb + cbase);
    const float q0 = bf2f((ushortT)(qv.x & 0xFFFF)), q1 = bf2f((ushortT)(qv.x >> 16));
    const float q2 = bf2f((ushortT)(qv.y & 0xFFFF)), q3 = bf2f((ushortT)(qv.y >> 16));

    const int beg = rowptr[d], end = rowptr[d + 1];
    float a0 = 0.f, a1 = 0.f, a2 = 0.f, a3 = 0.f, den = 0.f;

    int s = (beg < end) ? colsrc[beg] : 0;
    for (int i = beg; i < end; ++i) {
        const int snext = (i + 1 < end) ? colsrc[i + 1] : 0;
        const size_t sb = (size_t)s * DIM + t * 4;
        uint2 kv = *(const uint2*)(Kb + sb);
        uint2 vv = *(const uint2*)(Vb + sb);
        float k0 = bf2f((ushortT)(kv.x & 0xFFFF)), k1 = bf2f((ushortT)(kv.x >> 16));
        float k2 = bf2f((ushortT)(kv.y & 0xFFFF)), k3 = bf2f((ushortT)(kv.y >> 16));
        float p = q0 * k0 + q1 * k1 + q2 * k2 + q3 * k3;
        p += __shfl_xor(p, 1, 8);
        p += __shfl_xor(p, 2, 8);
        p += __shfl_xor(p, 4, 8);
        const float w = __expf(fminf(p * INV_SCALE, 60.0f));
        den += w;
        a0 += w * bf2f((ushortT)(vv.x & 0xFFFF));
        a1 += w * bf2f((ushortT)(vv.x >> 16));
        a2 += w * bf2f((ushortT)(vv.y & 0xFFFF));
        a3 += w * bf2f((ushortT)(vv.y >> 16));
        s = snext;
    }
    const float r = 1.0f / (den + SM_EPS);
    ushort4 o;
    o.x = f2bf(a0 * r); o.y = f2bf(a1 * r); o.z = f2bf(a2 * r); o.w = f2bf(a3 * r);
    *(ushort4*)(aggb + cbase) = o;
}

// ---------- host ----------
extern "C" void kernel_launch(void* const* d_in, const int* in_sizes, int n_in,
                              void* d_out, int out_size, void* d_ws, size_t ws_size,
                              hipStream_t stream)
{
    const void* slot_x = d_in[0];
    const void* dom_x  = d_in[1];
    const int* slot_edges = (const int*)d_in[2];
    const int* dom_edges  = (const int*)d_in[3];
    const int Ns = in_sizes[0] / DIM;    // 20000
    const int Nd = in_sizes[1] / DIM;    // 1000
    const int Es = in_sizes[2] / 2;      // 320000
    const int Ed = in_sizes[3] / 2;      // 16000

    const void* W[16];
    for (int i = 0; i < 16; ++i) W[i] = d_in[4 + i];

    // ---- workspace layout (slot-sized; domain reuses) ----
    char* p = (char*)d_ws;
    size_t o = 0;
    auto take = [&](size_t b) { void* r = p + o; o = (o + b + 255) & ~(size_t)255; return r; };
    const size_t nd2 = (size_t)Ns * DIM * 2;
    ushortT* xb   = (ushortT*)take(nd2);
    ushortT* Qb   = (ushortT*)take(nd2);
    ushortT* Kb   = (ushortT*)take(nd2);
    ushortT* Vb   = (ushortT*)take(nd2);
    ushortT* aggb = (ushortT*)take(nd2);
    ushortT* wT   = (ushortT*)take(4 * 65536 * 2);
    float*   biasF = (float*)take(4 * 256 * 4);
    int* rowptr = (int*)take((size_t)(Ns + 1) * 4);
    int* cursor = (int*)take((size_t)Ns * 4);
    int* count  = (int*)take((size_t)Ns * 4);
    int* colsrc = (int*)take((size_t)Es * 4);
    int* flag   = (int*)(p + ws_size - 256);

    hipLaunchKernelGGL(sniff_kernel, dim3(1), dim3(64), 0, stream,
                       (const ushortT*)slot_x, flag);

    auto branch = [&](const void* x, const int* edges, int N, int E,
                      const void* const* w, size_t outOff) {
        const int* src = edges;
        const int* dst = edges + E;
        const int n4 = N * DIM / 4;

        hipLaunchKernelGGL(convx_kernel, dim3((n4 + 255) / 256), dim3(256), 0, stream,
                           x, xb, n4, flag);
        hipLaunchKernelGGL(convw_kernel, dim3(257, 4), dim3(256), 0, stream,
                           w[0], w[2], w[4], w[6], w[1], w[3], w[5], w[7],
                           wT, biasF, flag);

        hipLaunchKernelGGL(csr_zero, dim3((N + 255) / 256), dim3(256), 0, stream, count, N);
        hipLaunchKernelGGL(csr_count, dim3((E + 255) / 256), dim3(256), 0, stream,
                           dst, count, E);
        hipLaunchKernelGGL(csr_scan, dim3(1), dim3(256), 0, stream,
                           count, rowptr, cursor, N);
        hipLaunchKernelGGL(csr_scatter, dim3((E + 255) / 256), dim3(256), 0, stream,
                           src, dst, cursor, colsrc, E);

        dim3 gg((N + BM - 1) / BM, DIM / BN);
        hipLaunchKernelGGL((gemm_mfma<1, false>), gg, dim3(256), 0, stream,
                           xb, wT + 0 * 65536, biasF + 0, (const void*)nullptr,
                           (void*)Qb, (size_t)0, N, flag);
        hipLaunchKernelGGL((gemm_mfma<1, false>), gg, dim3(256), 0, stream,
                           xb, wT + 1 * 65536, biasF + 256, (const void*)nullptr,
                           (void*)Kb, (size_t)0, N, flag);
        hipLaunchKernelGGL((gemm_mfma<1, false>), gg, dim3(256), 0, stream,
                           xb, wT + 2 * 65536, biasF + 512, (const void*)nullptr,
                           (void*)Vb, (size_t)0, N, flag);

        hipLaunchKernelGGL(attn_kernel, dim3(N), dim3(64), 0, stream,
                           Qb, Kb, Vb, rowptr, colsrc, aggb, N);

        hipLaunchKernelGGL((gemm_mfma<0, true>), gg, dim3(256), 0, stream,
                           aggb, wT + 3 * 65536, biasF + 768, x,
                           d_out, outOff, N, flag);
    };

    const void* slotW[8] = {W[0], W[1], W[2], W[3], W[4], W[5], W[6], W[7]};
    const void* domW[8]  = {W[8], W[9], W[10], W[11], W[12], W[13], W[14], W[15]};
    branch(slot_x, slot_edges, Ns, Es, slotW, 0);
    branch(dom_x,  dom_edges,  Nd, Ed, domW, (size_t)Ns * DIM);
}

// Round 5
// 317.148 us; speedup vs baseline: 2.7862x; 1.2179x over previous
//
#include <hip/hip_runtime.h>
#include <hip/hip_bf16.h>

#define DIM 256
#define NH 8
#define INV_SCALE 0.17677669529663687f   // 1/sqrt(32)
#define SM_EPS 1e-16f

typedef unsigned short ushortT;
typedef unsigned int uintT;
typedef __attribute__((ext_vector_type(8))) __bf16 bf16x8;
typedef __attribute__((ext_vector_type(4))) float f32x4;

// ---------- helpers ----------
__device__ __forceinline__ float bf2f(ushortT u) {
    return __uint_as_float(((uintT)u) << 16);
}
__device__ __forceinline__ ushortT f2bf(float f) {
    uintT u = __float_as_uint(f);
    u += 0x7FFFu + ((u >> 16) & 1u);     // round-to-nearest-even
    return (ushortT)(u >> 16);
}

// ---------- dtype sniffer (works — unchanged) ----------
__global__ void sniff_kernel(const ushortT* __restrict__ x, int* __restrict__ flag) {
    int lane = threadIdx.x & 63;
    ushortT u = x[lane * 2];
    int e = (u >> 7) & 0xFF;
    bool sane = ((u & 0x7FFFu) == 0) || (e >= 0x66 && e <= 0x90);
    unsigned long long m = __ballot(sane);
    if (lane == 0) *flag = (__popcll(m) >= 32) ? 1 : 0;
}

// ---------- convert x -> bf16 workspace ----------
__global__ __launch_bounds__(256) void convx_kernel(const void* __restrict__ x,
                                                    ushortT* __restrict__ xb,
                                                    int n4, const int* __restrict__ flag) {
    int i = blockIdx.x * 256 + threadIdx.x;
    if (i >= n4) return;
    if (*flag) {
        ((ushort4*)xb)[i] = ((const ushort4*)x)[i];
    } else {
        float4 v = ((const float4*)x)[i];
        ushort4 o;
        o.x = f2bf(v.x); o.y = f2bf(v.y); o.z = f2bf(v.z); o.w = f2bf(v.w);
        ((ushort4*)xb)[i] = o;
    }
}

// ---------- convert + transpose 4 weights, convert 4 biases ----------
__global__ __launch_bounds__(256) void convw_kernel(
        const void* w0, const void* w1, const void* w2, const void* w3,
        const void* b0, const void* b1, const void* b2, const void* b3,
        ushortT* __restrict__ wT, float* __restrict__ biasF,
        const int* __restrict__ flag)
{
    const void* ws_[4] = {w0, w1, w2, w3};
    const void* bs_[4] = {b0, b1, b2, b3};
    int which = blockIdx.y;
    bool m16 = (*flag != 0);
    if (blockIdx.x == 256) {
        const void* b = bs_[which];
        int i = threadIdx.x;
        float v = m16 ? bf2f(((const ushortT*)b)[i]) : ((const float*)b)[i];
        biasF[which * 256 + i] = v;
    } else {
        const void* w = ws_[which];
        int n = blockIdx.x, k = threadIdx.x;
        float v = m16 ? bf2f(((const ushortT*)w)[k * 256 + n])
                      : ((const float*)w)[k * 256 + n];
        wT[(size_t)which * 65536 + n * 256 + k] = f2bf(v);
    }
}

// ---------- CSR build ----------
__global__ __launch_bounds__(256) void csr_zero(int* __restrict__ count, int N) {
    int i = blockIdx.x * 256 + threadIdx.x;
    if (i < N) count[i] = 0;
}
__global__ __launch_bounds__(256) void csr_count(const int* __restrict__ dst,
                                                 int* __restrict__ count, int E) {
    int e = blockIdx.x * 256 + threadIdx.x;
    if (e < E) atomicAdd(&count[dst[e]], 1);
}
// stage 1: per-block sums of count (coalesced LDS reduce)
__global__ __launch_bounds__(256) void scan_bsum(const int* __restrict__ count,
                                                 int* __restrict__ bsum, int N) {
    __shared__ int sh[256];
    int t = threadIdx.x, i = blockIdx.x * 256 + t;
    sh[t] = (i < N) ? count[i] : 0;
    __syncthreads();
    #pragma unroll
    for (int off = 128; off > 0; off >>= 1) {
        if (t < off) sh[t] += sh[t + off];
        __syncthreads();
    }
    if (t == 0) bsum[blockIdx.x] = sh[0];
}
// stage 2: exclusive scan of nb (<=256) block sums, in place
__global__ __launch_bounds__(256) void scan_boff(int* __restrict__ bsum, int nb) {
    __shared__ int sh[256];
    int t = threadIdx.x;
    sh[t] = (t < nb) ? bsum[t] : 0;
    __syncthreads();
    for (int off = 1; off < 256; off <<= 1) {
        int v = (t >= off) ? sh[t - off] : 0;
        __syncthreads();
        sh[t] += v;
        __syncthreads();
    }
    if (t < nb) bsum[t] = (t == 0) ? 0 : sh[t - 1];
}
// stage 3: per-block exclusive scan + block offset -> rowptr, cursor
__global__ __launch_bounds__(256) void scan_write(const int* __restrict__ count,
                                                  const int* __restrict__ boff,
                                                  int* __restrict__ rowptr,
                                                  int* __restrict__ cursor, int N) {
    __shared__ int sh[256];
    int t = threadIdx.x, i = blockIdx.x * 256 + t;
    int v = (i < N) ? count[i] : 0;
    sh[t] = v;
    __syncthreads();
    for (int off = 1; off < 256; off <<= 1) {
        int u = (t >= off) ? sh[t - off] : 0;
        __syncthreads();
        sh[t] += u;
        __syncthreads();
    }
    int excl = boff[blockIdx.x] + ((t == 0) ? 0 : sh[t - 1]);
    if (i < N) {
        rowptr[i] = excl;
        cursor[i] = excl;
        if (i == N - 1) rowptr[N] = excl + v;
    }
}
__global__ __launch_bounds__(256) void csr_scatter(const int* __restrict__ src,
                                                   const int* __restrict__ dst,
                                                   int* __restrict__ cursor,
                                                   int* __restrict__ colsrc, int E) {
    int e = blockIdx.x * 256 + threadIdx.x;
    if (e < E) {
        int pos = atomicAdd(&cursor[dst[e]], 1);
        colsrc[pos] = src[e];
    }
}

// ---------- MFMA GEMM: C[M,256] = A[M,256](bf16) @ BT^T + bias ----------
// blockIdx.z selects weight/bias/output slice (QKV fusion). OK: 1 = bf16 ws
// out (z-strided), 0 = flag-dtype final out (+residual).
#define BM 128
#define BN 64
#define BK 32
template <int OK, bool RES>
__global__ __launch_bounds__(256) void gemm_mfma(
        const ushortT* __restrict__ A, const ushortT* __restrict__ BTbase,
        const float* __restrict__ biasF, const void* __restrict__ res,
        void* __restrict__ C, size_t outOff, size_t zStride, int M,
        const int* __restrict__ flag)
{
    __shared__ ushortT As[BM * BK];
    __shared__ ushortT Bs[BN * BK];
    const int z = blockIdx.z;
    const ushortT* BT = BTbase + (size_t)z * 65536;
    const float* bias = biasF + z * 256;
    const int tid  = threadIdx.x;
    const int wid  = tid >> 6;
    const int lane = tid & 63;
    const int row0 = blockIdx.x * BM;
    const int col0 = blockIdx.y * BN;

    const int r_i = tid >> 2;            // 0..63
    const int kq8 = (tid & 3) << 3;      // ushort offset 0,8,16,24
    const int m   = lane & 15;
    const int q   = lane >> 4;

    f32x4 acc[2][4];
    #pragma unroll
    for (int i = 0; i < 2; ++i)
        #pragma unroll
        for (int j = 0; j < 4; ++j)
            acc[i][j] = (f32x4){0.f, 0.f, 0.f, 0.f};

    const size_t rA0 = (size_t)min(row0 + r_i, M - 1) * DIM;
    const size_t rA1 = (size_t)min(row0 + 64 + r_i, M - 1) * DIM;
    const size_t rB  = (size_t)(col0 + r_i) * DIM;

    for (int k0 = 0; k0 < DIM; k0 += BK) {
        uint4 a0v = *(const uint4*)(A + rA0 + k0 + kq8);
        uint4 a1v = *(const uint4*)(A + rA1 + k0 + kq8);
        uint4 bv  = *(const uint4*)(BT + rB + k0 + kq8);
        __syncthreads();
        *(uint4*)&As[r_i * BK + kq8]        = a0v;
        *(uint4*)&As[(64 + r_i) * BK + kq8] = a1v;
        *(uint4*)&Bs[r_i * BK + kq8]        = bv;
        __syncthreads();

        bf16x8 af0 = *(const bf16x8*)&As[(wid * 32 + m) * BK + q * 8];
        bf16x8 af1 = *(const bf16x8*)&As[(wid * 32 + 16 + m) * BK + q * 8];
        #pragma unroll
        for (int j = 0; j < 4; ++j) {
            bf16x8 bf = *(const bf16x8*)&Bs[(j * 16 + m) * BK + q * 8];
            acc[0][j] = __builtin_amdgcn_mfma_f32_16x16x32_bf16(af0, bf, acc[0][j], 0, 0, 0);
            acc[1][j] = __builtin_amdgcn_mfma_f32_16x16x32_bf16(af1, bf, acc[1][j], 0, 0, 0);
        }
    }

    const bool m16 = (*flag != 0);
    #pragma unroll
    for (int i = 0; i < 2; ++i) {
        #pragma unroll
        for (int j = 0; j < 4; ++j) {
            const int col = col0 + j * 16 + m;
            const float bval = bias[col];
            #pragma unroll
            for (int r = 0; r < 4; ++r) {
                const int row = row0 + wid * 32 + i * 16 + q * 4 + r;
                if (row < M) {
                    float v = acc[i][j][r] + bval;
                    const size_t ridx = (size_t)row * DIM + col;
                    if constexpr (RES) {
                        v += m16 ? bf2f(((const ushortT*)res)[ridx])
                                 : ((const float*)res)[ridx];
                    }
                    if constexpr (OK == 1) {
                        ((ushortT*)C)[(size_t)z * zStride + ridx] = f2bf(v);
                    } else {
                        if (m16) ((ushortT*)C)[outOff + ridx] = f2bf(v);
                        else     ((float*)C)[outOff + ridx] = v;
                    }
                }
            }
        }
    }
}

// ---------- fused attention: 1 wave per dst node, 4 cols per lane ----------
__global__ __launch_bounds__(64) void attn_kernel(
        const ushortT* __restrict__ Qb, const ushortT* __restrict__ Kb,
        const ushortT* __restrict__ Vb, const int* __restrict__ rowptr,
        const int* __restrict__ colsrc, ushortT* __restrict__ aggb, int N)
{
    const int d = blockIdx.x;
    const int t = threadIdx.x;
    const size_t cbase = (size_t)d * DIM + t * 4;

    uint2 qv = *(const uint2*)(Qb + cbase);
    const float q0 = bf2f((ushortT)(qv.x & 0xFFFF)), q1 = bf2f((ushortT)(qv.x >> 16));
    const float q2 = bf2f((ushortT)(qv.y & 0xFFFF)), q3 = bf2f((ushortT)(qv.y >> 16));

    const int beg = rowptr[d], end = rowptr[d + 1];
    float a0 = 0.f, a1 = 0.f, a2 = 0.f, a3 = 0.f, den = 0.f;

    int s = (beg < end) ? colsrc[beg] : 0;
    for (int i = beg; i < end; ++i) {
        const int snext = (i + 1 < end) ? colsrc[i + 1] : 0;
        const size_t sb = (size_t)s * DIM + t * 4;
        uint2 kv = *(const uint2*)(Kb + sb);
        uint2 vv = *(const uint2*)(Vb + sb);
        float k0 = bf2f((ushortT)(kv.x & 0xFFFF)), k1 = bf2f((ushortT)(kv.x >> 16));
        float k2 = bf2f((ushortT)(kv.y & 0xFFFF)), k3 = bf2f((ushortT)(kv.y >> 16));
        float p = q0 * k0 + q1 * k1 + q2 * k2 + q3 * k3;
        p += __shfl_xor(p, 1, 8);
        p += __shfl_xor(p, 2, 8);
        p += __shfl_xor(p, 4, 8);
        const float w = __expf(fminf(p * INV_SCALE, 60.0f));
        den += w;
        a0 += w * bf2f((ushortT)(vv.x & 0xFFFF));
        a1 += w * bf2f((ushortT)(vv.x >> 16));
        a2 += w * bf2f((ushortT)(vv.y & 0xFFFF));
        a3 += w * bf2f((ushortT)(vv.y >> 16));
        s = snext;
    }
    const float r = 1.0f / (den + SM_EPS);
    ushort4 o;
    o.x = f2bf(a0 * r); o.y = f2bf(a1 * r); o.z = f2bf(a2 * r); o.w = f2bf(a3 * r);
    *(ushort4*)(aggb + cbase) = o;
}

// ---------- host ----------
extern "C" void kernel_launch(void* const* d_in, const int* in_sizes, int n_in,
                              void* d_out, int out_size, void* d_ws, size_t ws_size,
                              hipStream_t stream)
{
    const void* slot_x = d_in[0];
    const void* dom_x  = d_in[1];
    const int* slot_edges = (const int*)d_in[2];
    const int* dom_edges  = (const int*)d_in[3];
    const int Ns = in_sizes[0] / DIM;    // 20000
    const int Nd = in_sizes[1] / DIM;    // 1000
    const int Es = in_sizes[2] / 2;      // 320000
    const int Ed = in_sizes[3] / 2;      // 16000

    const void* W[16];
    for (int i = 0; i < 16; ++i) W[i] = d_in[4 + i];

    // ---- workspace layout (slot-sized; domain reuses) ----
    char* p = (char*)d_ws;
    size_t o = 0;
    auto take = [&](size_t b) { void* r = p + o; o = (o + b + 255) & ~(size_t)255; return r; };
    const size_t nd2 = (size_t)Ns * DIM * 2;   // multiple of 256
    ushortT* xb   = (ushortT*)take(nd2);
    ushortT* Qb   = (ushortT*)take(nd2);       // Qb/Kb/Vb contiguous: stride Ns*DIM
    ushortT* Kb   = (ushortT*)take(nd2);
    ushortT* Vb   = (ushortT*)take(nd2);
    ushortT* aggb = (ushortT*)take(nd2);
    ushortT* wT   = (ushortT*)take(4 * 65536 * 2);
    float*   biasF = (float*)take(4 * 256 * 4);
    int* rowptr = (int*)take((size_t)(Ns + 1) * 4);
    int* cursor = (int*)take((size_t)Ns * 4);
    int* count  = (int*)take((size_t)Ns * 4);
    int* bsum   = (int*)take(256 * 4);
    int* colsrc = (int*)take((size_t)Es * 4);
    int* flag   = (int*)(p + ws_size - 256);

    hipLaunchKernelGGL(sniff_kernel, dim3(1), dim3(64), 0, stream,
                       (const ushortT*)slot_x, flag);

    auto branch = [&](const void* x, const int* edges, int N, int E,
                      const void* const* w, size_t outOff) {
        const int* src = edges;
        const int* dst = edges + E;
        const int n4 = N * DIM / 4;
        const int nb = (N + 255) / 256;

        hipLaunchKernelGGL(convx_kernel, dim3((n4 + 255) / 256), dim3(256), 0, stream,
                           x, xb, n4, flag);
        hipLaunchKernelGGL(convw_kernel, dim3(257, 4), dim3(256), 0, stream,
                           w[0], w[2], w[4], w[6], w[1], w[3], w[5], w[7],
                           wT, biasF, flag);

        hipLaunchKernelGGL(csr_zero, dim3(nb), dim3(256), 0, stream, count, N);
        hipLaunchKernelGGL(csr_count, dim3((E + 255) / 256), dim3(256), 0, stream,
                           dst, count, E);
        hipLaunchKernelGGL(scan_bsum, dim3(nb), dim3(256), 0, stream, count, bsum, N);
        hipLaunchKernelGGL(scan_boff, dim3(1), dim3(256), 0, stream, bsum, nb);
        hipLaunchKernelGGL(scan_write, dim3(nb), dim3(256), 0, stream,
                           count, bsum, rowptr, cursor, N);
        hipLaunchKernelGGL(csr_scatter, dim3((E + 255) / 256), dim3(256), 0, stream,
                           src, dst, cursor, colsrc, E);

        // fused Q/K/V GEMM via blockIdx.z
        dim3 gq((N + BM - 1) / BM, DIM / BN, 3);
        hipLaunchKernelGGL((gemm_mfma<1, false>), gq, dim3(256), 0, stream,
                           xb, wT, biasF, (const void*)nullptr,
                           (void*)Qb, (size_t)0, (size_t)Ns * DIM, N, flag);

        hipLaunchKernelGGL(attn_kernel, dim3(N), dim3(64), 0, stream,
                           Qb, Kb, Vb, rowptr, colsrc, aggb, N);

        dim3 gg((N + BM - 1) / BM, DIM / BN, 1);
        hipLaunchKernelGGL((gemm_mfma<0, true>), gg, dim3(256), 0, stream,
                           aggb, wT + 3 * 65536, biasF + 768, x,
                           d_out, outOff, (size_t)0, N, flag);
    };

    const void* slotW[8] = {W[0], W[1], W[2], W[3], W[4], W[5], W[6], W[7]};
    const void* domW[8]  = {W[8], W[9], W[10], W[11], W[12], W[13], W[14], W[15]};
    branch(slot_x, slot_edges, Ns, Es, slotW, 0);
    branch(dom_x,  dom_edges,  Nd, Ed, domW, (size_t)Ns * DIM);
}

// Round 6
// 273.548 us; speedup vs baseline: 3.2303x; 1.1594x over previous
//
#include <hip/hip_runtime.h>
#include <hip/hip_bf16.h>

#define DIM 256
#define INV_SCALE 0.17677669529663687f   // 1/sqrt(32)
#define SM_EPS 1e-16f
#define BM 128
#define BN 64
#define BK 32

typedef unsigned short ushortT;
typedef unsigned int uintT;
typedef __attribute__((ext_vector_type(8))) __bf16 bf16x8;
typedef __attribute__((ext_vector_type(4))) float f32x4;

// ---------- helpers ----------
__device__ __forceinline__ float bf2f(ushortT u) {
    return __uint_as_float(((uintT)u) << 16);
}
__device__ __forceinline__ ushortT f2bf(float f) {
    uintT u = __float_as_uint(f);
    u += 0x7FFFu + ((u >> 16) & 1u);     // round-to-nearest-even
    return (ushortT)(u >> 16);
}

struct WPack { const void* w[8]; const void* b[8]; };

// ---------- dtype sniffer (proven — unchanged) ----------
__global__ void sniff_kernel(const ushortT* __restrict__ x, int* __restrict__ flag) {
    int lane = threadIdx.x & 63;
    ushortT u = x[lane * 2];
    int e = (u >> 7) & 0xFF;
    bool sane = ((u & 0x7FFFu) == 0) || (e >= 0x66 && e <= 0x90);
    unsigned long long m = __ballot(sane);
    if (lane == 0) *flag = (__popcll(m) >= 32) ? 1 : 0;
}

// ---------- convert x -> bf16 (both graphs, y-split) ----------
__global__ __launch_bounds__(256) void convx2(const void* __restrict__ xs,
                                              const void* __restrict__ xd,
                                              ushortT* __restrict__ xbs,
                                              ushortT* __restrict__ xbd,
                                              int n4s, int n4d,
                                              const int* __restrict__ flag) {
    const int y = blockIdx.y;
    const int n4 = y ? n4d : n4s;
    int i = blockIdx.x * 256 + threadIdx.x;
    if (i >= n4) return;
    const void* x = y ? xd : xs;
    ushortT* xb = y ? xbd : xbs;
    if (*flag) {
        ((ushort4*)xb)[i] = ((const ushort4*)x)[i];
    } else {
        float4 v = ((const float4*)x)[i];
        ushort4 o;
        o.x = f2bf(v.x); o.y = f2bf(v.y); o.z = f2bf(v.z); o.w = f2bf(v.w);
        ((ushort4*)xb)[i] = o;
    }
}

// ---------- convert + transpose 8 weights, convert 8 biases ----------
__global__ __launch_bounds__(256) void convw_kernel(WPack pk,
                                                    ushortT* __restrict__ wT,
                                                    float* __restrict__ biasF,
                                                    const int* __restrict__ flag) {
    const int which = blockIdx.y;
    const bool m16 = (*flag != 0);
    if (blockIdx.x == 256) {
        const void* b = pk.b[which];
        int i = threadIdx.x;
        float v = m16 ? bf2f(((const ushortT*)b)[i]) : ((const float*)b)[i];
        biasF[which * 256 + i] = v;
    } else {
        const void* w = pk.w[which];
        int n = blockIdx.x, k = threadIdx.x;
        float v = m16 ? bf2f(((const ushortT*)w)[k * 256 + n])
                      : ((const float*)w)[k * 256 + n];
        wT[(size_t)which * 65536 + n * 256 + k] = f2bf(v);
    }
}

// ---------- CSR build (both graphs, y-split) ----------
__global__ __launch_bounds__(256) void csr_zero2(int* __restrict__ cs, int* __restrict__ cd,
                                                 int Ns_, int Nd_) {
    const int y = blockIdx.y;
    int N = y ? Nd_ : Ns_;
    int* c = y ? cd : cs;
    int i = blockIdx.x * 256 + threadIdx.x;
    if (i < N) c[i] = 0;
}
__global__ __launch_bounds__(256) void csr_count2(const int* __restrict__ ds,
                                                  const int* __restrict__ dd,
                                                  int* __restrict__ cs, int* __restrict__ cd,
                                                  int Es, int Ed) {
    const int y = blockIdx.y;
    int E = y ? Ed : Es;
    int e = blockIdx.x * 256 + threadIdx.x;
    if (e >= E) return;
    const int* dst = y ? dd : ds;
    int* c = y ? cd : cs;
    atomicAdd(&c[dst[e]], 1);
}
__global__ __launch_bounds__(256) void scan_bsum2(const int* __restrict__ cs,
                                                  const int* __restrict__ cd,
                                                  int* __restrict__ bss, int* __restrict__ bsd,
                                                  int Ns_, int Nd_) {
    __shared__ int sh[256];
    const int y = blockIdx.y;
    int N = y ? Nd_ : Ns_;
    const int* c = y ? cd : cs;
    int* bs = y ? bsd : bss;
    int t = threadIdx.x, i = blockIdx.x * 256 + t;
    sh[t] = (i < N) ? c[i] : 0;
    __syncthreads();
    #pragma unroll
    for (int off = 128; off > 0; off >>= 1) {
        if (t < off) sh[t] += sh[t + off];
        __syncthreads();
    }
    if (t == 0) bs[blockIdx.x] = sh[0];
}
__global__ __launch_bounds__(256) void scan_boff2(int* __restrict__ bss, int* __restrict__ bsd,
                                                  int nbs_, int nbd_) {
    __shared__ int sh[256];
    const int y = blockIdx.y;
    int nb = y ? nbd_ : nbs_;
    int* bs = y ? bsd : bss;
    int t = threadIdx.x;
    sh[t] = (t < nb) ? bs[t] : 0;
    __syncthreads();
    for (int off = 1; off < 256; off <<= 1) {
        int v = (t >= off) ? sh[t - off] : 0;
        __syncthreads();
        sh[t] += v;
        __syncthreads();
    }
    if (t < nb) bs[t] = (t == 0) ? 0 : sh[t - 1];
}
__global__ __launch_bounds__(256) void scan_write2(const int* __restrict__ cs,
                                                   const int* __restrict__ cd,
                                                   const int* __restrict__ bss,
                                                   const int* __restrict__ bsd,
                                                   int* __restrict__ rps, int* __restrict__ rpd,
                                                   int* __restrict__ curs, int* __restrict__ curd,
                                                   int Ns_, int Nd_) {
    __shared__ int sh[256];
    const int y = blockIdx.y;
    int N = y ? Nd_ : Ns_;
    const int* c = y ? cd : cs;
    const int* bo = y ? bsd : bss;
    int* rp = y ? rpd : rps;
    int* cur = y ? curd : curs;
    int t = threadIdx.x, i = blockIdx.x * 256 + t;
    int v = (i < N) ? c[i] : 0;
    sh[t] = v;
    __syncthreads();
    for (int off = 1; off < 256; off <<= 1) {
        int u = (t >= off) ? sh[t - off] : 0;
        __syncthreads();
        sh[t] += u;
        __syncthreads();
    }
    int excl = bo[blockIdx.x] + ((t == 0) ? 0 : sh[t - 1]);
    if (i < N) {
        rp[i] = excl;
        cur[i] = excl;
        if (i == N - 1) rp[N] = excl + v;
    }
}
__global__ __launch_bounds__(256) void csr_scatter2(const int* __restrict__ ss,
                                                    const int* __restrict__ ds,
                                                    const int* __restrict__ sd,
                                                    const int* __restrict__ dd,
                                                    int* __restrict__ curs, int* __restrict__ curd,
                                                    int* __restrict__ cols, int* __restrict__ cold,
                                                    int Es, int Ed) {
    const int y = blockIdx.y;
    int E = y ? Ed : Es;
    int e = blockIdx.x * 256 + threadIdx.x;
    if (e >= E) return;
    const int* src = y ? sd : ss;
    const int* dst = y ? dd : ds;
    int* cur = y ? curd : curs;
    int* col = y ? cold : cols;
    int pos = atomicAdd(&cur[dst[e]], 1);
    col[pos] = src[e];
}

// ---------- MFMA GEMM core (shared by QKV and OUT variants) ----------
__device__ __forceinline__ void gemm_core(const ushortT* __restrict__ A,
                                          const ushortT* __restrict__ BT,
                                          int row0, int col0, int M,
                                          f32x4 (&acc)[2][4]) {
    __shared__ ushortT As[BM * BK];
    __shared__ ushortT Bs[BN * BK];
    const int tid  = threadIdx.x;
    const int wid  = tid >> 6;
    const int lane = tid & 63;
    const int r_i = tid >> 2;
    const int kq8 = (tid & 3) << 3;
    const int m   = lane & 15;
    const int q   = lane >> 4;

    const size_t rA0 = (size_t)min(row0 + r_i, M - 1) * DIM;
    const size_t rA1 = (size_t)min(row0 + 64 + r_i, M - 1) * DIM;
    const size_t rB  = (size_t)(col0 + r_i) * DIM;

    for (int k0 = 0; k0 < DIM; k0 += BK) {
        uint4 a0v = *(const uint4*)(A + rA0 + k0 + kq8);
        uint4 a1v = *(const uint4*)(A + rA1 + k0 + kq8);
        uint4 bv  = *(const uint4*)(BT + rB + k0 + kq8);
        __syncthreads();
        *(uint4*)&As[r_i * BK + kq8]        = a0v;
        *(uint4*)&As[(64 + r_i) * BK + kq8] = a1v;
        *(uint4*)&Bs[r_i * BK + kq8]        = bv;
        __syncthreads();

        bf16x8 af0 = *(const bf16x8*)&As[(wid * 32 + m) * BK + q * 8];
        bf16x8 af1 = *(const bf16x8*)&As[(wid * 32 + 16 + m) * BK + q * 8];
        #pragma unroll
        for (int j = 0; j < 4; ++j) {
            bf16x8 bf = *(const bf16x8*)&Bs[(j * 16 + m) * BK + q * 8];
            acc[0][j] = __builtin_amdgcn_mfma_f32_16x16x32_bf16(af0, bf, acc[0][j], 0, 0, 0);
            acc[1][j] = __builtin_amdgcn_mfma_f32_16x16x32_bf16(af1, bf, acc[1][j], 0, 0, 0);
        }
    }
}

// QKV fused: z in [0,3) picks weight; x-split picks slot/domain region.
__global__ __launch_bounds__(256) void gemm_qkv(
        const ushortT* __restrict__ As_, const ushortT* __restrict__ Ad_,
        const ushortT* __restrict__ wT, const float* __restrict__ biasF,
        ushortT* __restrict__ Cs, ushortT* __restrict__ Cd,
        size_t zss, size_t zsd, int Ms, int Md, int nbs)
{
    const int z = blockIdx.z;
    const bool dom = (int)blockIdx.x >= nbs;
    const int bx = dom ? blockIdx.x - nbs : blockIdx.x;
    const ushortT* A = dom ? Ad_ : As_;
    const int M = dom ? Md : Ms;
    const int widx = z + (dom ? 4 : 0);
    const ushortT* BT = wT + (size_t)widx * 65536;
    const float* bias = biasF + widx * 256;
    ushortT* C = (dom ? Cd : Cs) + (size_t)z * (dom ? zsd : zss);

    const int row0 = bx * BM;
    const int col0 = blockIdx.y * BN;
    const int wid = threadIdx.x >> 6, lane = threadIdx.x & 63;
    const int m = lane & 15, q = lane >> 4;

    f32x4 acc[2][4];
    #pragma unroll
    for (int i = 0; i < 2; ++i)
        #pragma unroll
        for (int j = 0; j < 4; ++j) acc[i][j] = (f32x4){0.f, 0.f, 0.f, 0.f};

    gemm_core(A, BT, row0, col0, M, acc);

    #pragma unroll
    for (int i = 0; i < 2; ++i)
        #pragma unroll
        for (int j = 0; j < 4; ++j) {
            const int col = col0 + j * 16 + m;
            const float bval = bias[col];
            #pragma unroll
            for (int r = 0; r < 4; ++r) {
                const int row = row0 + wid * 32 + i * 16 + q * 4 + r;
                if (row < M)
                    C[(size_t)row * DIM + col] = f2bf(acc[i][j][r] + bval);
            }
        }
}

// OUT: agg @ wo + bias + residual(x) -> d_out (flag dtype), x-split regions.
__global__ __launch_bounds__(256) void gemm_out(
        const ushortT* __restrict__ As_, const ushortT* __restrict__ Ad_,
        const ushortT* __restrict__ wT, const float* __restrict__ biasF,
        const void* __restrict__ xs, const void* __restrict__ xd,
        void* __restrict__ dout, int Ms, int Md, int nbs,
        const int* __restrict__ flag)
{
    const bool dom = (int)blockIdx.x >= nbs;
    const int bx = dom ? blockIdx.x - nbs : blockIdx.x;
    const ushortT* A = dom ? Ad_ : As_;
    const int M = dom ? Md : Ms;
    const int widx = 3 + (dom ? 4 : 0);
    const ushortT* BT = wT + (size_t)widx * 65536;
    const float* bias = biasF + widx * 256;
    const void* res = dom ? xd : xs;
    const size_t outOff = dom ? (size_t)Ms * DIM : 0;

    const int row0 = bx * BM;
    const int col0 = blockIdx.y * BN;
    const int wid = threadIdx.x >> 6, lane = threadIdx.x & 63;
    const int m = lane & 15, q = lane >> 4;

    f32x4 acc[2][4];
    #pragma unroll
    for (int i = 0; i < 2; ++i)
        #pragma unroll
        for (int j = 0; j < 4; ++j) acc[i][j] = (f32x4){0.f, 0.f, 0.f, 0.f};

    gemm_core(A, BT, row0, col0, M, acc);

    const bool m16 = (*flag != 0);
    #pragma unroll
    for (int i = 0; i < 2; ++i)
        #pragma unroll
        for (int j = 0; j < 4; ++j) {
            const int col = col0 + j * 16 + m;
            const float bval = bias[col];
            #pragma unroll
            for (int r = 0; r < 4; ++r) {
                const int row = row0 + wid * 32 + i * 16 + q * 4 + r;
                if (row < M) {
                    const size_t ridx = (size_t)row * DIM + col;
                    float v = acc[i][j][r] + bval;
                    v += m16 ? bf2f(((const ushortT*)res)[ridx])
                             : ((const float*)res)[ridx];
                    if (m16) ((ushortT*)dout)[outOff + ridx] = f2bf(v);
                    else     ((float*)dout)[outOff + ridx] = v;
                }
            }
        }
}

// ---------- fused attention: 256 thr = 4 waves = 4 dst nodes ----------
__global__ __launch_bounds__(256) void attn_kernel(
        const ushortT* __restrict__ Qs, const ushortT* __restrict__ Ks,
        const ushortT* __restrict__ Vs, const int* __restrict__ rps,
        const int* __restrict__ css, ushortT* __restrict__ aggs,
        const ushortT* __restrict__ Qd_, const ushortT* __restrict__ Kd_,
        const ushortT* __restrict__ Vd_, const int* __restrict__ rpd,
        const int* __restrict__ csd, ushortT* __restrict__ aggd,
        int Ns_, int Ntot)
{
    const int g = blockIdx.x * 4 + (threadIdx.x >> 6);
    if (g >= Ntot) return;
    const bool dom = g >= Ns_;
    const int d = dom ? g - Ns_ : g;
    const int t = threadIdx.x & 63;
    const ushortT* Qb = dom ? Qd_ : Qs;
    const ushortT* Kb = dom ? Kd_ : Ks;
    const ushortT* Vb = dom ? Vd_ : Vs;
    const int* rowptr = dom ? rpd : rps;
    const int* colsrc = dom ? csd : css;
    ushortT* aggb = dom ? aggd : aggs;

    const size_t cbase = (size_t)d * DIM + t * 4;
    uint2 qv = *(const uint2*)(Qb + cbase);
    const float q0 = bf2f((ushortT)(qv.x & 0xFFFF)), q1 = bf2f((ushortT)(qv.x >> 16));
    const float q2 = bf2f((ushortT)(qv.y & 0xFFFF)), q3 = bf2f((ushortT)(qv.y >> 16));

    const int beg = rowptr[d], end = rowptr[d + 1];
    float a0 = 0.f, a1 = 0.f, a2 = 0.f, a3 = 0.f, den = 0.f;

    if (beg < end) {
        int s0 = colsrc[beg];
        size_t sb = (size_t)s0 * DIM + t * 4;
        uint2 kv = *(const uint2*)(Kb + sb);
        uint2 vv = *(const uint2*)(Vb + sb);
        for (int i = beg; i < end; ++i) {
            uint2 kvc = kv, vvc = vv;
            // branchless one-ahead prefetch (last iter re-loads current row)
            int sn = colsrc[(i + 1 < end) ? i + 1 : i];
            size_t sbn = (size_t)sn * DIM + t * 4;
            kv = *(const uint2*)(Kb + sbn);
            vv = *(const uint2*)(Vb + sbn);

            float k0 = bf2f((ushortT)(kvc.x & 0xFFFF)), k1 = bf2f((ushortT)(kvc.x >> 16));
            float k2 = bf2f((ushortT)(kvc.y & 0xFFFF)), k3 = bf2f((ushortT)(kvc.y >> 16));
            float p = q0 * k0 + q1 * k1 + q2 * k2 + q3 * k3;
            p += __shfl_xor(p, 1, 8);
            p += __shfl_xor(p, 2, 8);
            p += __shfl_xor(p, 4, 8);
            const float w = __expf(fminf(p * INV_SCALE, 60.0f));
            den += w;
            a0 += w * bf2f((ushortT)(vvc.x & 0xFFFF));
            a1 += w * bf2f((ushortT)(vvc.x >> 16));
            a2 += w * bf2f((ushortT)(vvc.y & 0xFFFF));
            a3 += w * bf2f((ushortT)(vvc.y >> 16));
        }
    }
    const float r = 1.0f / (den + SM_EPS);
    ushort4 o;
    o.x = f2bf(a0 * r); o.y = f2bf(a1 * r); o.z = f2bf(a2 * r); o.w = f2bf(a3 * r);
    *(ushort4*)(aggb + cbase) = o;
}

// ---------- host ----------
extern "C" void kernel_launch(void* const* d_in, const int* in_sizes, int n_in,
                              void* d_out, int out_size, void* d_ws, size_t ws_size,
                              hipStream_t stream)
{
    const void* slot_x = d_in[0];
    const void* dom_x  = d_in[1];
    const int* slot_edges = (const int*)d_in[2];
    const int* dom_edges  = (const int*)d_in[3];
    const int Ns = in_sizes[0] / DIM;    // 20000
    const int Nd = in_sizes[1] / DIM;    // 1000
    const int Es = in_sizes[2] / 2;      // 320000
    const int Ed = in_sizes[3] / 2;      // 16000

    WPack pk;
    for (int i = 0; i < 8; ++i) { pk.w[i] = d_in[4 + 2 * i]; pk.b[i] = d_in[5 + 2 * i]; }

    // ---- workspace ----
    char* p = (char*)d_ws;
    size_t o = 0;
    auto take = [&](size_t b) { void* r = p + o; o = (o + b + 255) & ~(size_t)255; return r; };
    const size_t ndS = (size_t)Ns * DIM;             // elements
    const size_t ndD = (size_t)Nd * DIM;
    ushortT* xb_s  = (ushortT*)take(ndS * 2);
    ushortT* qkv_s = (ushortT*)take(3 * ndS * 2);    // Q|K|V contiguous
    ushortT* agg_s = (ushortT*)take(ndS * 2);
    ushortT* xb_d  = (ushortT*)take(ndD * 2);
    ushortT* qkv_d = (ushortT*)take(3 * ndD * 2);
    ushortT* agg_d = (ushortT*)take(ndD * 2);
    ushortT* wT    = (ushortT*)take(8 * 65536 * 2);
    float*   biasF = (float*)take(8 * 256 * 4);
    int* rp_s  = (int*)take((size_t)(Ns + 1) * 4);
    int* cur_s = (int*)take((size_t)Ns * 4);
    int* cnt_s = (int*)take((size_t)Ns * 4);
    int* bs_s  = (int*)take(256 * 4);
    int* col_s = (int*)take((size_t)Es * 4);
    int* rp_d  = (int*)take((size_t)(Nd + 1) * 4);
    int* cur_d = (int*)take((size_t)Nd * 4);
    int* cnt_d = (int*)take((size_t)Nd * 4);
    int* bs_d  = (int*)take(256 * 4);
    int* col_d = (int*)take((size_t)Ed * 4);
    int* flag  = (int*)(p + ws_size - 256);

    const int* src_s = slot_edges;
    const int* dst_s = slot_edges + Es;
    const int* src_d = dom_edges;
    const int* dst_d = dom_edges + Ed;

    const int n4s = Ns * DIM / 4, n4d = Nd * DIM / 4;
    const int nbN = (Ns + 255) / 256;                // covers both graphs
    const int nbE = (Es + 255) / 256;
    const int nbs = (Ns + BM - 1) / BM;              // 157
    const int nbd = (Nd + BM - 1) / BM;              // 8

    hipLaunchKernelGGL(sniff_kernel, dim3(1), dim3(64), 0, stream,
                       (const ushortT*)slot_x, flag);
    hipLaunchKernelGGL(convx2, dim3((n4s + 255) / 256, 2), dim3(256), 0, stream,
                       slot_x, dom_x, xb_s, xb_d, n4s, n4d, flag);
    hipLaunchKernelGGL(convw_kernel, dim3(257, 8), dim3(256), 0, stream,
                       pk, wT, biasF, flag);

    hipLaunchKernelGGL(csr_zero2, dim3(nbN, 2), dim3(256), 0, stream,
                       cnt_s, cnt_d, Ns, Nd);
    hipLaunchKernelGGL(csr_count2, dim3(nbE, 2), dim3(256), 0, stream,
                       dst_s, dst_d, cnt_s, cnt_d, Es, Ed);
    hipLaunchKernelGGL(scan_bsum2, dim3(nbN, 2), dim3(256), 0, stream,
                       cnt_s, cnt_d, bs_s, bs_d, Ns, Nd);
    hipLaunchKernelGGL(scan_boff2, dim3(1, 2), dim3(256), 0, stream,
                       bs_s, bs_d, nbN, (Nd + 255) / 256);
    hipLaunchKernelGGL(scan_write2, dim3(nbN, 2), dim3(256), 0, stream,
                       cnt_s, cnt_d, bs_s, bs_d, rp_s, rp_d, cur_s, cur_d, Ns, Nd);
    hipLaunchKernelGGL(csr_scatter2, dim3(nbE, 2), dim3(256), 0, stream,
                       src_s, dst_s, src_d, dst_d, cur_s, cur_d, col_s, col_d, Es, Ed);

    hipLaunchKernelGGL(gemm_qkv, dim3(nbs + nbd, DIM / BN, 3), dim3(256), 0, stream,
                       xb_s, xb_d, wT, biasF, qkv_s, qkv_d, ndS, ndD, Ns, Nd, nbs);

    const int Ntot = Ns + Nd;
    hipLaunchKernelGGL(attn_kernel, dim3((Ntot + 3) / 4), dim3(256), 0, stream,
                       qkv_s, qkv_s + ndS, qkv_s + 2 * ndS, rp_s, col_s, agg_s,
                       qkv_d, qkv_d + ndD, qkv_d + 2 * ndD, rp_d, col_d, agg_d,
                       Ns, Ntot);

    hipLaunchKernelGGL(gemm_out, dim3(nbs + nbd, DIM / BN), dim3(256), 0, stream,
                       agg_s, agg_d, wT, biasF, slot_x, dom_x, d_out, Ns, Nd, nbs, flag);
}

// Round 7
// 264.480 us; speedup vs baseline: 3.3410x; 1.0343x over previous
//
#include <hip/hip_runtime.h>
#include <hip/hip_bf16.h>

#define DIM 256
#define INV_SCALE 0.17677669529663687f   // 1/sqrt(32)
#define SM_EPS 1e-16f
#define BM 128
#define BN 64
#define BK 32

typedef unsigned short ushortT;
typedef unsigned int uintT;
typedef __attribute__((ext_vector_type(8))) __bf16 bf16x8;
typedef __attribute__((ext_vector_type(4))) float f32x4;

// ---------- helpers ----------
__device__ __forceinline__ float bf2f(ushortT u) {
    return __uint_as_float(((uintT)u) << 16);
}
__device__ __forceinline__ ushortT f2bf(float f) {
    uintT u = __float_as_uint(f);
    u += 0x7FFFu + ((u >> 16) & 1u);     // round-to-nearest-even
    return (ushortT)(u >> 16);
}

struct WPack { const void* w[8]; const void* b[8]; };

// ---------- dtype sniffer (proven — unchanged) ----------
__global__ void sniff_kernel(const ushortT* __restrict__ x, int* __restrict__ flag) {
    int lane = threadIdx.x & 63;
    ushortT u = x[lane * 2];
    int e = (u >> 7) & 0xFF;
    bool sane = ((u & 0x7FFFu) == 0) || (e >= 0x66 && e <= 0x90);
    unsigned long long m = __ballot(sane);
    if (lane == 0) *flag = (__popcll(m) >= 32) ? 1 : 0;
}

// ---------- prep: convert x (slot/dom) + zero CSR counters, y-region split ---
__global__ __launch_bounds__(256) void prep_kernel(
        const void* __restrict__ xs, const void* __restrict__ xd,
        ushortT* __restrict__ xbs, ushortT* __restrict__ xbd,
        int* __restrict__ cs, int* __restrict__ cd,
        int n4s, int n4d, int Ns_, int Nd_, const int* __restrict__ flag) {
    const int y = blockIdx.y;
    int i = blockIdx.x * 256 + threadIdx.x;
    if (y >= 2) {                         // zero counters
        int N = (y == 3) ? Nd_ : Ns_;
        int* c = (y == 3) ? cd : cs;
        if (i < N) c[i] = 0;
        return;
    }
    const int n4 = y ? n4d : n4s;
    if (i >= n4) return;
    const void* x = y ? xd : xs;
    ushortT* xb = y ? xbd : xbs;
    if (*flag) {
        ((ushort4*)xb)[i] = ((const ushort4*)x)[i];
    } else {
        float4 v = ((const float4*)x)[i];
        ushort4 o;
        o.x = f2bf(v.x); o.y = f2bf(v.y); o.z = f2bf(v.z); o.w = f2bf(v.w);
        ((ushort4*)xb)[i] = o;
    }
}

// ---------- convert + transpose 8 weights, convert 8 biases ----------
__global__ __launch_bounds__(256) void convw_kernel(WPack pk,
                                                    ushortT* __restrict__ wT,
                                                    float* __restrict__ biasF,
                                                    const int* __restrict__ flag) {
    const int which = blockIdx.y;
    const bool m16 = (*flag != 0);
    if (blockIdx.x == 256) {
        const void* b = pk.b[which];
        int i = threadIdx.x;
        float v = m16 ? bf2f(((const ushortT*)b)[i]) : ((const float*)b)[i];
        biasF[which * 256 + i] = v;
    } else {
        const void* w = pk.w[which];
        int n = blockIdx.x, k = threadIdx.x;
        float v = m16 ? bf2f(((const ushortT*)w)[k * 256 + n])
                      : ((const float*)w)[k * 256 + n];
        wT[(size_t)which * 65536 + n * 256 + k] = f2bf(v);
    }
}

// ---------- CSR build (both graphs, y-split) ----------
__global__ __launch_bounds__(256) void csr_count2(const int* __restrict__ ds,
                                                  const int* __restrict__ dd,
                                                  int* __restrict__ cs, int* __restrict__ cd,
                                                  int Es, int Ed) {
    const int y = blockIdx.y;
    int E = y ? Ed : Es;
    int e = blockIdx.x * 256 + threadIdx.x;
    if (e >= E) return;
    const int* dst = y ? dd : ds;
    int* c = y ? cd : cs;
    atomicAdd(&c[dst[e]], 1);
}
__global__ __launch_bounds__(256) void scan_bsum2(const int* __restrict__ cs,
                                                  const int* __restrict__ cd,
                                                  int* __restrict__ bss, int* __restrict__ bsd,
                                                  int Ns_, int Nd_) {
    __shared__ int sh[256];
    const int y = blockIdx.y;
    int N = y ? Nd_ : Ns_;
    const int* c = y ? cd : cs;
    int* bs = y ? bsd : bss;
    int t = threadIdx.x, i = blockIdx.x * 256 + t;
    sh[t] = (i < N) ? c[i] : 0;
    __syncthreads();
    #pragma unroll
    for (int off = 128; off > 0; off >>= 1) {
        if (t < off) sh[t] += sh[t + off];
        __syncthreads();
    }
    if (t == 0) bs[blockIdx.x] = sh[0];
}
__global__ __launch_bounds__(256) void scan_boff2(int* __restrict__ bss, int* __restrict__ bsd,
                                                  int nbs_, int nbd_) {
    __shared__ int sh[256];
    const int y = blockIdx.y;
    int nb = y ? nbd_ : nbs_;
    int* bs = y ? bsd : bss;
    int t = threadIdx.x;
    sh[t] = (t < nb) ? bs[t] : 0;
    __syncthreads();
    for (int off = 1; off < 256; off <<= 1) {
        int v = (t >= off) ? sh[t - off] : 0;
        __syncthreads();
        sh[t] += v;
        __syncthreads();
    }
    if (t < nb) bs[t] = (t == 0) ? 0 : sh[t - 1];
}
__global__ __launch_bounds__(256) void scan_write2(const int* __restrict__ cs,
                                                   const int* __restrict__ cd,
                                                   const int* __restrict__ bss,
                                                   const int* __restrict__ bsd,
                                                   int* __restrict__ rps, int* __restrict__ rpd,
                                                   int* __restrict__ curs, int* __restrict__ curd,
                                                   int Ns_, int Nd_) {
    __shared__ int sh[256];
    const int y = blockIdx.y;
    int N = y ? Nd_ : Ns_;
    const int* c = y ? cd : cs;
    const int* bo = y ? bsd : bss;
    int* rp = y ? rpd : rps;
    int* cur = y ? curd : curs;
    int t = threadIdx.x, i = blockIdx.x * 256 + t;
    int v = (i < N) ? c[i] : 0;
    sh[t] = v;
    __syncthreads();
    for (int off = 1; off < 256; off <<= 1) {
        int u = (t >= off) ? sh[t - off] : 0;
        __syncthreads();
        sh[t] += u;
        __syncthreads();
    }
    int excl = bo[blockIdx.x] + ((t == 0) ? 0 : sh[t - 1]);
    if (i < N) {
        rp[i] = excl;
        cur[i] = excl;
        if (i == N - 1) rp[N] = excl + v;
    }
}
__global__ __launch_bounds__(256) void csr_scatter2(const int* __restrict__ ss,
                                                    const int* __restrict__ ds,
                                                    const int* __restrict__ sd,
                                                    const int* __restrict__ dd,
                                                    int* __restrict__ curs, int* __restrict__ curd,
                                                    int* __restrict__ cols, int* __restrict__ cold,
                                                    int Es, int Ed) {
    const int y = blockIdx.y;
    int E = y ? Ed : Es;
    int e = blockIdx.x * 256 + threadIdx.x;
    if (e >= E) return;
    const int* src = y ? sd : ss;
    const int* dst = y ? dd : ds;
    int* cur = y ? curd : curs;
    int* col = y ? cold : cols;
    int pos = atomicAdd(&cur[dst[e]], 1);
    col[pos] = src[e];
}

// ---------- MFMA GEMM core ----------
__device__ __forceinline__ void gemm_core(const ushortT* __restrict__ A,
                                          const ushortT* __restrict__ BT,
                                          int row0, int col0, int M,
                                          f32x4 (&acc)[2][4]) {
    __shared__ ushortT As[BM * BK];
    __shared__ ushortT Bs[BN * BK];
    const int tid  = threadIdx.x;
    const int wid  = tid >> 6;
    const int lane = tid & 63;
    const int r_i = tid >> 2;
    const int kq8 = (tid & 3) << 3;
    const int m   = lane & 15;
    const int q   = lane >> 4;

    const size_t rA0 = (size_t)min(row0 + r_i, M - 1) * DIM;
    const size_t rA1 = (size_t)min(row0 + 64 + r_i, M - 1) * DIM;
    const size_t rB  = (size_t)(col0 + r_i) * DIM;

    for (int k0 = 0; k0 < DIM; k0 += BK) {
        uint4 a0v = *(const uint4*)(A + rA0 + k0 + kq8);
        uint4 a1v = *(const uint4*)(A + rA1 + k0 + kq8);
        uint4 bv  = *(const uint4*)(BT + rB + k0 + kq8);
        __syncthreads();
        *(uint4*)&As[r_i * BK + kq8]        = a0v;
        *(uint4*)&As[(64 + r_i) * BK + kq8] = a1v;
        *(uint4*)&Bs[r_i * BK + kq8]        = bv;
        __syncthreads();

        bf16x8 af0 = *(const bf16x8*)&As[(wid * 32 + m) * BK + q * 8];
        bf16x8 af1 = *(const bf16x8*)&As[(wid * 32 + 16 + m) * BK + q * 8];
        #pragma unroll
        for (int j = 0; j < 4; ++j) {
            bf16x8 bf = *(const bf16x8*)&Bs[(j * 16 + m) * BK + q * 8];
            acc[0][j] = __builtin_amdgcn_mfma_f32_16x16x32_bf16(af0, bf, acc[0][j], 0, 0, 0);
            acc[1][j] = __builtin_amdgcn_mfma_f32_16x16x32_bf16(af1, bf, acc[1][j], 0, 0, 0);
        }
    }
}

// QKV fused: z picks weight; x-split picks slot/domain region.
__global__ __launch_bounds__(256) void gemm_qkv(
        const ushortT* __restrict__ As_, const ushortT* __restrict__ Ad_,
        const ushortT* __restrict__ wT, const float* __restrict__ biasF,
        ushortT* __restrict__ Cs, ushortT* __restrict__ Cd,
        size_t zss, size_t zsd, int Ms, int Md, int nbs)
{
    const int z = blockIdx.z;
    const bool dom = (int)blockIdx.x >= nbs;
    const int bx = dom ? blockIdx.x - nbs : blockIdx.x;
    const ushortT* A = dom ? Ad_ : As_;
    const int M = dom ? Md : Ms;
    const int widx = z + (dom ? 4 : 0);
    const ushortT* BT = wT + (size_t)widx * 65536;
    const float* bias = biasF + widx * 256;
    ushortT* C = (dom ? Cd : Cs) + (size_t)z * (dom ? zsd : zss);

    const int row0 = bx * BM;
    const int col0 = blockIdx.y * BN;
    const int wid = threadIdx.x >> 6, lane = threadIdx.x & 63;
    const int m = lane & 15, q = lane >> 4;

    f32x4 acc[2][4];
    #pragma unroll
    for (int i = 0; i < 2; ++i)
        #pragma unroll
        for (int j = 0; j < 4; ++j) acc[i][j] = (f32x4){0.f, 0.f, 0.f, 0.f};

    gemm_core(A, BT, row0, col0, M, acc);

    #pragma unroll
    for (int i = 0; i < 2; ++i)
        #pragma unroll
        for (int j = 0; j < 4; ++j) {
            const int col = col0 + j * 16 + m;
            const float bval = bias[col];
            #pragma unroll
            for (int r = 0; r < 4; ++r) {
                const int row = row0 + wid * 32 + i * 16 + q * 4 + r;
                if (row < M)
                    C[(size_t)row * DIM + col] = f2bf(acc[i][j][r] + bval);
            }
        }
}

// OUT: agg @ wo + bias + residual(x) -> d_out (flag dtype), x-split regions.
__global__ __launch_bounds__(256) void gemm_out(
        const ushortT* __restrict__ As_, const ushortT* __restrict__ Ad_,
        const ushortT* __restrict__ wT, const float* __restrict__ biasF,
        const void* __restrict__ xs, const void* __restrict__ xd,
        void* __restrict__ dout, int Ms, int Md, int nbs,
        const int* __restrict__ flag)
{
    const bool dom = (int)blockIdx.x >= nbs;
    const int bx = dom ? blockIdx.x - nbs : blockIdx.x;
    const ushortT* A = dom ? Ad_ : As_;
    const int M = dom ? Md : Ms;
    const int widx = 3 + (dom ? 4 : 0);
    const ushortT* BT = wT + (size_t)widx * 65536;
    const float* bias = biasF + widx * 256;
    const void* res = dom ? xd : xs;
    const size_t outOff = dom ? (size_t)Ms * DIM : 0;

    const int row0 = bx * BM;
    const int col0 = blockIdx.y * BN;
    const int wid = threadIdx.x >> 6, lane = threadIdx.x & 63;
    const int m = lane & 15, q = lane >> 4;

    f32x4 acc[2][4];
    #pragma unroll
    for (int i = 0; i < 2; ++i)
        #pragma unroll
        for (int j = 0; j < 4; ++j) acc[i][j] = (f32x4){0.f, 0.f, 0.f, 0.f};

    gemm_core(A, BT, row0, col0, M, acc);

    const bool m16 = (*flag != 0);
    #pragma unroll
    for (int i = 0; i < 2; ++i)
        #pragma unroll
        for (int j = 0; j < 4; ++j) {
            const int col = col0 + j * 16 + m;
            const float bval = bias[col];
            #pragma unroll
            for (int r = 0; r < 4; ++r) {
                const int row = row0 + wid * 32 + i * 16 + q * 4 + r;
                if (row < M) {
                    const size_t ridx = (size_t)row * DIM + col;
                    float v = acc[i][j][r] + bval;
                    v += m16 ? bf2f(((const ushortT*)res)[ridx])
                             : ((const float*)res)[ridx];
                    if (m16) ((ushortT*)dout)[outOff + ridx] = f2bf(v);
                    else     ((float*)dout)[outOff + ridx] = v;
                }
            }
        }
}

// ---------- fused attention: 256 thr = 4 waves = 4 dst nodes ----------
// Edge loop unrolled x4: 8 independent K/V row loads in flight per wave.
__global__ __launch_bounds__(256) void attn_kernel(
        const ushortT* __restrict__ Qs, const ushortT* __restrict__ Ks,
        const ushortT* __restrict__ Vs, const int* __restrict__ rps,
        const int* __restrict__ css, ushortT* __restrict__ aggs,
        const ushortT* __restrict__ Qd_, const ushortT* __restrict__ Kd_,
        const ushortT* __restrict__ Vd_, const int* __restrict__ rpd,
        const int* __restrict__ csd, ushortT* __restrict__ aggd,
        int Ns_, int Ntot)
{
    const int g = blockIdx.x * 4 + (threadIdx.x >> 6);
    if (g >= Ntot) return;
    const bool dom = g >= Ns_;
    const int d = dom ? g - Ns_ : g;
    const int t = threadIdx.x & 63;
    const ushortT* Qb = dom ? Qd_ : Qs;
    const ushortT* Kb = dom ? Kd_ : Ks;
    const ushortT* Vb = dom ? Vd_ : Vs;
    const int* rowptr = dom ? rpd : rps;
    const int* colsrc = dom ? csd : css;
    ushortT* aggb = dom ? aggd : aggs;

    const int t4 = t * 4;
    const size_t cbase = (size_t)d * DIM + t4;
    uint2 qv = *(const uint2*)(Qb + cbase);
    const float q0 = bf2f((ushortT)(qv.x & 0xFFFF)), q1 = bf2f((ushortT)(qv.x >> 16));
    const float q2 = bf2f((ushortT)(qv.y & 0xFFFF)), q3 = bf2f((ushortT)(qv.y >> 16));

    float a0 = 0.f, a1 = 0.f, a2 = 0.f, a3 = 0.f, den = 0.f;

    auto PROC = [&](uint2 kvc, uint2 vvc) {
        float k0 = bf2f((ushortT)(kvc.x & 0xFFFF)), k1 = bf2f((ushortT)(kvc.x >> 16));
        float k2 = bf2f((ushortT)(kvc.y & 0xFFFF)), k3 = bf2f((ushortT)(kvc.y >> 16));
        float p = q0 * k0 + q1 * k1 + q2 * k2 + q3 * k3;
        p += __shfl_xor(p, 1, 8);
        p += __shfl_xor(p, 2, 8);
        p += __shfl_xor(p, 4, 8);
        const float w = __expf(fminf(p * INV_SCALE, 60.0f));
        den += w;
        a0 += w * bf2f((ushortT)(vvc.x & 0xFFFF));
        a1 += w * bf2f((ushortT)(vvc.x >> 16));
        a2 += w * bf2f((ushortT)(vvc.y & 0xFFFF));
        a3 += w * bf2f((ushortT)(vvc.y >> 16));
    };

    const int beg = rowptr[d], end = rowptr[d + 1];
    int i = beg;
    for (; i + 4 <= end; i += 4) {
        const int s0 = colsrc[i], s1 = colsrc[i + 1];
        const int s2 = colsrc[i + 2], s3 = colsrc[i + 3];
        const size_t b0 = (size_t)s0 * DIM + t4, b1 = (size_t)s1 * DIM + t4;
        const size_t b2 = (size_t)s2 * DIM + t4, b3 = (size_t)s3 * DIM + t4;
        uint2 k0v = *(const uint2*)(Kb + b0), v0v = *(const uint2*)(Vb + b0);
        uint2 k1v = *(const uint2*)(Kb + b1), v1v = *(const uint2*)(Vb + b1);
        uint2 k2v = *(const uint2*)(Kb + b2), v2v = *(const uint2*)(Vb + b2);
        uint2 k3v = *(const uint2*)(Kb + b3), v3v = *(const uint2*)(Vb + b3);
        PROC(k0v, v0v); PROC(k1v, v1v); PROC(k2v, v2v); PROC(k3v, v3v);
    }
    for (; i < end; ++i) {
        const size_t sb = (size_t)colsrc[i] * DIM + t4;
        uint2 kv = *(const uint2*)(Kb + sb);
        uint2 vv = *(const uint2*)(Vb + sb);
        PROC(kv, vv);
    }

    const float r = 1.0f / (den + SM_EPS);
    ushort4 o;
    o.x = f2bf(a0 * r); o.y = f2bf(a1 * r); o.z = f2bf(a2 * r); o.w = f2bf(a3 * r);
    *(ushort4*)(aggb + cbase) = o;
}

// ---------- host ----------
extern "C" void kernel_launch(void* const* d_in, const int* in_sizes, int n_in,
                              void* d_out, int out_size, void* d_ws, size_t ws_size,
                              hipStream_t stream)
{
    const void* slot_x = d_in[0];
    const void* dom_x  = d_in[1];
    const int* slot_edges = (const int*)d_in[2];
    const int* dom_edges  = (const int*)d_in[3];
    const int Ns = in_sizes[0] / DIM;    // 20000
    const int Nd = in_sizes[1] / DIM;    // 1000
    const int Es = in_sizes[2] / 2;      // 320000
    const int Ed = in_sizes[3] / 2;      // 16000

    WPack pk;
    for (int i = 0; i < 8; ++i) { pk.w[i] = d_in[4 + 2 * i]; pk.b[i] = d_in[5 + 2 * i]; }

    // ---- workspace ----
    char* p = (char*)d_ws;
    size_t o = 0;
    auto take = [&](size_t b) { void* r = p + o; o = (o + b + 255) & ~(size_t)255; return r; };
    const size_t ndS = (size_t)Ns * DIM;             // elements
    const size_t ndD = (size_t)Nd * DIM;
    ushortT* xb_s  = (ushortT*)take(ndS * 2);
    ushortT* qkv_s = (ushortT*)take(3 * ndS * 2);    // Q|K|V contiguous
    ushortT* agg_s = (ushortT*)take(ndS * 2);
    ushortT* xb_d  = (ushortT*)take(ndD * 2);
    ushortT* qkv_d = (ushortT*)take(3 * ndD * 2);
    ushortT* agg_d = (ushortT*)take(ndD * 2);
    ushortT* wT    = (ushortT*)take(8 * 65536 * 2);
    float*   biasF = (float*)take(8 * 256 * 4);
    int* rp_s  = (int*)take((size_t)(Ns + 1) * 4);
    int* cur_s = (int*)take((size_t)Ns * 4);
    int* cnt_s = (int*)take((size_t)Ns * 4);
    int* bs_s  = (int*)take(256 * 4);
    int* col_s = (int*)take((size_t)Es * 4);
    int* rp_d  = (int*)take((size_t)(Nd + 1) * 4);
    int* cur_d = (int*)take((size_t)Nd * 4);
    int* cnt_d = (int*)take((size_t)Nd * 4);
    int* bs_d  = (int*)take(256 * 4);
    int* col_d = (int*)take((size_t)Ed * 4);
    int* flag  = (int*)(p + ws_size - 256);

    const int* src_s = slot_edges;
    const int* dst_s = slot_edges + Es;
    const int* src_d = dom_edges;
    const int* dst_d = dom_edges + Ed;

    const int n4s = Ns * DIM / 4, n4d = Nd * DIM / 4;
    const int nbN = (Ns + 255) / 256;
    const int nbE = (Es + 255) / 256;
    const int nbs = (Ns + BM - 1) / BM;              // 157
    const int nbd = (Nd + BM - 1) / BM;              // 8

    hipLaunchKernelGGL(sniff_kernel, dim3(1), dim3(64), 0, stream,
                       (const ushortT*)slot_x, flag);
    hipLaunchKernelGGL(prep_kernel, dim3((n4s + 255) / 256, 4), dim3(256), 0, stream,
                       slot_x, dom_x, xb_s, xb_d, cnt_s, cnt_d,
                       n4s, n4d, Ns, Nd, flag);
    hipLaunchKernelGGL(convw_kernel, dim3(257, 8), dim3(256), 0, stream,
                       pk, wT, biasF, flag);

    hipLaunchKernelGGL(csr_count2, dim3(nbE, 2), dim3(256), 0, stream,
                       dst_s, dst_d, cnt_s, cnt_d, Es, Ed);
    hipLaunchKernelGGL(scan_bsum2, dim3(nbN, 2), dim3(256), 0, stream,
                       cnt_s, cnt_d, bs_s, bs_d, Ns, Nd);
    hipLaunchKernelGGL(scan_boff2, dim3(1, 2), dim3(256), 0, stream,
                       bs_s, bs_d, nbN, (Nd + 255) / 256);
    hipLaunchKernelGGL(scan_write2, dim3(nbN, 2), dim3(256), 0, stream,
                       cnt_s, cnt_d, bs_s, bs_d, rp_s, rp_d, cur_s, cur_d, Ns, Nd);
    hipLaunchKernelGGL(csr_scatter2, dim3(nbE, 2), dim3(256), 0, stream,
                       src_s, dst_s, src_d, dst_d, cur_s, cur_d, col_s, col_d, Es, Ed);

    hipLaunchKernelGGL(gemm_qkv, dim3(nbs + nbd, DIM / BN, 3), dim3(256), 0, stream,
                       xb_s, xb_d, wT, biasF, qkv_s, qkv_d, ndS, ndD, Ns, Nd, nbs);

    const int Ntot = Ns + Nd;
    hipLaunchKernelGGL(attn_kernel, dim3((Ntot + 3) / 4), dim3(256), 0, stream,
                       qkv_s, qkv_s + ndS, qkv_s + 2 * ndS, rp_s, col_s, agg_s,
                       qkv_d, qkv_d + ndD, qkv_d + 2 * ndD, rp_d, col_d, agg_d,
                       Ns, Ntot);

    hipLaunchKernelGGL(gemm_out, dim3(nbs + nbd, DIM / BN), dim3(256), 0, stream,
                       agg_s, agg_d, wT, biasF, slot_x, dom_x, d_out, Ns, Nd, nbs, flag);
}